// Round 4
// baseline (329.075 us; speedup 1.0000x reference)
//
#include <hip/hip_runtime.h>
#include <hip/hip_bf16.h>
#include <stdint.h>

// Problem constants (from reference)
#define DMODEL 1024
#define M_TOK  16384   // B*L = 4*4096

typedef __attribute__((ext_vector_type(8))) short short8;   // 8 x bf16 (4 VGPRs)
typedef __attribute__((ext_vector_type(4))) float f32x4;    // MFMA C/D frag

// Pack two fp32 -> two bf16 (RNE) in one dword via v_perm_b32.
__device__ __forceinline__ unsigned int pack2_bf16(float f0, float f1) {
    unsigned int u0 = __builtin_bit_cast(unsigned int, f0);
    unsigned int u1 = __builtin_bit_cast(unsigned int, f1);
    u0 += 0x7fffu + ((u0 >> 16) & 1u);
    u1 += 0x7fffu + ((u1 >> 16) & 1u);
    return __builtin_amdgcn_perm(u1, u0, 0x07060302);  // mem order f0, f1
}

// async global->LDS, 16B per lane. LDS dest = wave-uniform base + lane*16.
__device__ __forceinline__ void gload_lds16(const void* g, void* l) {
    __builtin_amdgcn_global_load_lds(
        (const __attribute__((address_space(1))) void*)g,
        (__attribute__((address_space(3))) void*)l, 16, 0, 0);
}

// ---------------- Phase 0: plan = parallel compaction + R conversion --------
// Blocks 0..63: compact 256 tokens each (ballot rank + one atomicAdd; order
// across blocks is nondeterministic but output values are order-invariant:
// each agent row's result depends only on its own token, and GEMM scatters by
// orig[]). Blocks 64..95: convert R rows 32 each to bf16 Rb.
__global__ void plan_kernel(const int* __restrict__ roles, const float* __restrict__ Rm,
                            int* __restrict__ orig, int* __restrict__ n_agent,
                            __hip_bfloat16* __restrict__ Rb) {
    const int t = threadIdx.x;
    if (blockIdx.x < 64) {
        const int tok  = blockIdx.x * 256 + t;
        const int pred = (roles[tok] == 1);
        const int lane = t & 63;
        const int wave = t >> 6;
        unsigned long long b = __ballot(pred);
        const int rank   = __popcll(b & ((1ull << lane) - 1ull));
        const int wtotal = __popcll(b);
        __shared__ int woff[4];
        __shared__ int sbase;
        if (lane == 0) woff[wave] = wtotal;
        __syncthreads();
        if (t == 0) {
            int s0 = woff[0], s1 = woff[1], s2 = woff[2], s3 = woff[3];
            sbase = atomicAdd(n_agent, s0 + s1 + s2 + s3);
            woff[0] = 0; woff[1] = s0; woff[2] = s0 + s1; woff[3] = s0 + s1 + s2;
        }
        __syncthreads();
        if (pred) orig[sbase + woff[wave] + rank] = tok;
    } else {
        const int rblk = blockIdx.x - 64;           // 32 rows of R each
        const size_t base = (size_t)rblk * 32 * DMODEL;
        for (int s = 0; s < 32; ++s) {
            const size_t idx = base + s * 1024 + t * 4;
            float4 v = *(const float4*)(Rm + idx);
            uint2 p = make_uint2(pack2_bf16(v.x, v.y), pack2_bf16(v.z, v.w));
            *(uint2*)((unsigned short*)Rb + idx) = p;
        }
    }
}

// ---------------- Phase 1: mega = GEMM-from-emb (agents) + user copy --------
// Blocks [0,1024): GEMM. linear id = n*128 + m, so the 8 n-blocks sharing an
//   A-tile are spaced 128 apart -> same id%8 -> same XCD -> A sliver re-reads
//   hit that XCD's L2 (round-1's 8x over-fetch came from the opposite order).
//   A staged fp32->bf16 in-kernel (no Xc round-trip); B via global_load_lds.
// Blocks [1024,2048): copy user rows exact fp32 emb->out (overlaps GEMM).
__global__ void mega(const int* __restrict__ ids, const int* __restrict__ roles,
                     const float* __restrict__ emb, const __hip_bfloat16* __restrict__ Rb,
                     const int* __restrict__ orig, const int* __restrict__ n_agent_p,
                     float* __restrict__ out) {
    __shared__ __hip_bfloat16 As[128 * 32];
    __shared__ __hip_bfloat16 Bs[128 * 32];
    __shared__ int s_oj[128];
    __shared__ int s_srow[128];

    const int tid  = threadIdx.x;
    const int lane = tid & 63;
    const int wave = tid >> 6;

    if (blockIdx.x >= 1024) {
        // ---- user-row passthrough: 16 token rows per block, 4 per wave ----
        const int cb = blockIdx.x - 1024;
#pragma unroll
        for (int r = 0; r < 4; ++r) {
            const int row = cb * 16 + wave * 4 + r;
            if (roles[row] != 1) {
                const float* src = emb + (size_t)ids[row] * DMODEL;
                float* dst = out + (size_t)row * DMODEL;
#pragma unroll
                for (int c = 0; c < 4; ++c) {
                    const int idx = c * 256 + lane * 4;
                    *(float4*)(dst + idx) = *(const float4*)(src + idx);
                }
            }
        }
        return;
    }

    // ---- GEMM over compacted agent rows ----
    const int na = *n_agent_p;
    const int mt = blockIdx.x & 127;
    const int nt = blockIdx.x >> 7;
    const int m0 = mt * 128;
    if (m0 >= na) return;
    const int n0 = nt * 128;

    const int quad = lane >> 4;
    const int l15  = lane & 15;
    const int wr   = wave >> 1;
    const int wc   = wave & 1;

    if (tid < 128) {
        const int j  = m0 + tid;
        const int oj = (j < na) ? orig[j] : -1;
        s_oj[tid]   = oj;
        s_srow[tid] = (oj >= 0) ? ids[oj] : 0;   // pad rows read emb row 0 (zeros)
    }
    __syncthreads();

    // A-staging: 2 threads per tile-row, 16 fp32 (64B) each, pack -> bf16 LDS
    const int sr = tid >> 1;
    const int sh = tid & 1;
    const float* aRow = emb + (size_t)s_srow[sr] * DMODEL + sh * 16;

    // B-staging via global_load_lds: wave w, issue q -> 16-row group
    const int st_row = lane >> 2;
    const int st_k   = (lane & 3) * 8;
    const int rg0 = wave * 16;
    const int rg1 = (4 + wave) * 16;
    const __hip_bfloat16* bG = Rb + (size_t)n0 * DMODEL;

    f32x4 acc[4][4] = {};

    for (int k0 = 0; k0 < DMODEL; k0 += 32) {
        // global A loads issued before the barrier (overlap prior MFMAs)
        float4 a0 = *(const float4*)(aRow + k0);
        float4 a1 = *(const float4*)(aRow + k0 + 4);
        float4 a2 = *(const float4*)(aRow + k0 + 8);
        float4 a3 = *(const float4*)(aRow + k0 + 12);

        __syncthreads();   // previous tile's frag reads complete
        gload_lds16(bG + (size_t)(rg0 + st_row) * DMODEL + k0 + st_k, &Bs[rg0 * 32]);
        gload_lds16(bG + (size_t)(rg1 + st_row) * DMODEL + k0 + st_k, &Bs[rg1 * 32]);

        uint4 p0 = make_uint4(pack2_bf16(a0.x, a0.y), pack2_bf16(a0.z, a0.w),
                              pack2_bf16(a1.x, a1.y), pack2_bf16(a1.z, a1.w));
        uint4 p1 = make_uint4(pack2_bf16(a2.x, a2.y), pack2_bf16(a2.z, a2.w),
                              pack2_bf16(a3.x, a3.y), pack2_bf16(a3.z, a3.w));
        *(uint4*)&As[sr * 32 + sh * 16]     = p0;
        *(uint4*)&As[sr * 32 + sh * 16 + 8] = p1;

        __syncthreads();   // barrier drains vmcnt + lgkmcnt -> tile ready

        short8 af[4], bfr[4];
#pragma unroll
        for (int i = 0; i < 4; ++i)
            af[i] = *(const short8*)&As[(wr * 64 + i * 16 + l15) * 32 + quad * 8];
#pragma unroll
        for (int j = 0; j < 4; ++j)
            bfr[j] = *(const short8*)&Bs[(wc * 64 + j * 16 + l15) * 32 + quad * 8];
#pragma unroll
        for (int i = 0; i < 4; ++i)
#pragma unroll
            for (int j = 0; j < 4; ++j)
                acc[i][j] = __builtin_amdgcn_mfma_f32_16x16x32_bf16(af[i], bfr[j], acc[i][j], 0, 0, 0);
    }

    // epilogue: C/D layout col=l15, row=quad*4+reg; scatter to orig token row
    const int colbase = n0 + wc * 64 + l15;
#pragma unroll
    for (int ti = 0; ti < 4; ++ti) {
        const int rowb = wr * 64 + ti * 16 + quad * 4;
#pragma unroll
        for (int r = 0; r < 4; ++r) {
            const int row = rowb + r;
            const int oj  = s_oj[row];
            if (oj >= 0) {
                float* dst = out + (size_t)oj * DMODEL + colbase;
#pragma unroll
                for (int tj = 0; tj < 4; ++tj)
                    dst[tj * 16] = acc[ti][tj][r];
            }
        }
    }
}

extern "C" void kernel_launch(void* const* d_in, const int* in_sizes, int n_in,
                              void* d_out, int out_size, void* d_ws, size_t ws_size,
                              hipStream_t stream) {
    const int*   ids   = (const int*)d_in[0];
    const int*   roles = (const int*)d_in[1];
    const float* emb   = (const float*)d_in[2];
    const float* Rm    = (const float*)d_in[3];
    float*       out   = (float*)d_out;

    // ws layout: Rb 2MB | orig 64KB | n_agent
    __hip_bfloat16* Rb = (__hip_bfloat16*)d_ws;
    int* orig    = (int*)(Rb + (size_t)DMODEL * DMODEL);
    int* n_agent = orig + M_TOK;

    hipMemsetAsync(n_agent, 0, sizeof(int), stream);   // ws is poisoned each call
    plan_kernel<<<96, 256, 0, stream>>>(roles, Rm, orig, n_agent, Rb);
    mega<<<2048, 256, 0, stream>>>(ids, roles, emb, Rb, orig, n_agent, out);
}